// Round 1
// baseline (6149.179 us; speedup 1.0000x reference)
//
#include <hip/hip_runtime.h>
#include <hip/hip_bf16.h>

#define SLEN 128
#define BAT 64
#define EDIM 512
#define HDIM 1024
#define VOC 10000
#define VPAD 10112     // 79 * 128
#define NWG_REC 192

typedef short v8s __attribute__((ext_vector_type(8)));
typedef float v4f __attribute__((ext_vector_type(4)));
typedef unsigned short u16;

__device__ __forceinline__ u16 f2bf(float f) {
  unsigned u = __float_as_uint(f);
  u += 0x7fffu + ((u >> 16) & 1u);   // RNE
  return (u16)(u >> 16);
}
__device__ __forceinline__ float bf2f(u16 b) {
  return __uint_as_float(((unsigned)b) << 16);
}
__device__ __forceinline__ float sigm(float x) { return 1.f / (1.f + __expf(-x)); }
__device__ __forceinline__ float tanh_f(float x) { return 1.f - 2.f / (1.f + __expf(2.f * x)); }

// ---------------- hierarchical grid barrier (192 WGs, 8 sub-counters) -------------
__device__ __forceinline__ void gbar(int* bar) {
  __syncthreads();
  if (threadIdx.x == 0) {
    int grp = blockIdx.x & 7;
    int* sub  = bar + grp * 32;      // 128B apart
    int* root = bar + 256;
    int* gen  = bar + 288;
    const int per = NWG_REC / 8;     // 24
    int g = __hip_atomic_load(gen, __ATOMIC_RELAXED, __HIP_MEMORY_SCOPE_AGENT);
    int a = __hip_atomic_fetch_add(sub, 1, __ATOMIC_ACQ_REL, __HIP_MEMORY_SCOPE_AGENT);
    if (a == per - 1) {
      __hip_atomic_store(sub, 0, __ATOMIC_RELAXED, __HIP_MEMORY_SCOPE_AGENT);
      int r = __hip_atomic_fetch_add(root, 1, __ATOMIC_ACQ_REL, __HIP_MEMORY_SCOPE_AGENT);
      if (r == 7) {
        __hip_atomic_store(root, 0, __ATOMIC_RELAXED, __HIP_MEMORY_SCOPE_AGENT);
        __hip_atomic_fetch_add(gen, 1, __ATOMIC_RELEASE, __HIP_MEMORY_SCOPE_AGENT);
      }
    }
    while (__hip_atomic_load(gen, __ATOMIC_RELAXED, __HIP_MEMORY_SCOPE_AGENT) == g)
      __builtin_amdgcn_s_sleep(2);
    __builtin_amdgcn_fence(__ATOMIC_ACQUIRE, "agent");
  }
  __syncthreads();
}

// 64x32 output tile, K=1024, A (64,1024) bf16 row-major, B rows (32,1024) bf16.
// Wave w owns rows 16w..16w+15; 2 column fragments of 16.
__device__ __forceinline__ void tile_gemm64x32(
    const u16* __restrict__ A, const u16* __restrict__ B,
    int w, int l, v4f acc[2]) {
  const int lr = l & 15;
  const int lk = (l >> 4) * 8;
  const u16* ap  = A + (w * 16 + lr) * HDIM + lk;
  const u16* bp0 = B + lr * HDIM + lk;
  const u16* bp1 = B + (16 + lr) * HDIM + lk;
  acc[0] = v4f{0.f, 0.f, 0.f, 0.f};
  acc[1] = v4f{0.f, 0.f, 0.f, 0.f};
#pragma unroll 8
  for (int ks = 0; ks < 32; ++ks) {
    v8s a  = *(const v8s*)(ap + ks * 32);
    v8s b0 = *(const v8s*)(bp0 + ks * 32);
    v8s b1 = *(const v8s*)(bp1 + ks * 32);
    acc[0] = __builtin_amdgcn_mfma_f32_16x16x32_bf16(a, b0, acc[0], 0, 0, 0);
    acc[1] = __builtin_amdgcn_mfma_f32_16x16x32_bf16(a, b1, acc[1], 0, 0, 0);
  }
}

// ---------------- persistent 2-layer GRU recurrence -------------------------------
// Per tick T (2 barriers):
//  P1: G1 rz0(T) [wg 0..63] | G3 xp1(T-1) [wg 64..159] | G5 ht1(T-2)+h1-update [wg 160..191]
//  P2: G2 ht0(T)+h0-update [wg 0..31] | G4 rz1(T-1) [wg 32..95]
__global__ void __launch_bounds__(256) k_recur(
    const u16* __restrict__ Uh0b, const u16* __restrict__ Wx1b, const u16* __restrict__ Uh1b,
    const float* __restrict__ b0, const float* __restrict__ b1,
    const u16* __restrict__ xa0,
    float* __restrict__ h0f, u16* __restrict__ h0b,
    float* __restrict__ h1f, u16* __restrict__ h1b,
    u16* __restrict__ a2, float* __restrict__ z0,
    u16* __restrict__ a5, float* __restrict__ z1,
    float* __restrict__ xp1,
    u16* __restrict__ hs1,
    float* __restrict__ outh,
    int* __restrict__ bar) {
  const int wg = blockIdx.x;
  const int t = threadIdx.x;
  const int w = t >> 6;
  const int l = t & 63;
  const int lr = l & 15;
  const int rbase = w * 16 + ((l >> 4) << 2);

  for (int T = 0; T <= SLEN + 1; ++T) {
    // ---------------- Phase 1 ----------------
    if (wg < 64) {
      if (T < SLEN) {
        const int c0 = wg * 32;
        const int g = c0 >> 10;
        const int o0 = c0 & 1023;
        v4f acc[2];
        tile_gemm64x32(h0b, Uh0b + (size_t)c0 * HDIM, w, l, acc);
#pragma unroll
        for (int fc = 0; fc < 2; ++fc)
#pragma unroll
          for (int r = 0; r < 4; ++r) {
            int b = rbase + r;
            int o = o0 + fc * 16 + lr;
            float x = acc[fc][r] + bf2f(xa0[((T * 3 + g) * BAT + b) * HDIM + o]) + b0[g * HDIM + o];
            float s = sigm(x);
            if (g == 0) a2[b * HDIM + o] = f2bf(s * h0f[b * HDIM + o]);
            else        z0[b * HDIM + o] = s;
          }
      }
    } else if (wg < 160) {
      if (T >= 1 && T <= SLEN) {
        const int c0 = (wg - 64) * 32;
        v4f acc[2];
        tile_gemm64x32(h0b, Wx1b + (size_t)c0 * HDIM, w, l, acc);
        float* xp = xp1 + ((T - 1) & 1) * (BAT * 3 * HDIM);
#pragma unroll
        for (int fc = 0; fc < 2; ++fc)
#pragma unroll
          for (int r = 0; r < 4; ++r) {
            int b = rbase + r;
            int n = c0 + fc * 16 + lr;
            xp[b * 3072 + n] = acc[fc][r];
          }
      }
    } else {
      if (T >= 2) {
        const int t5 = T - 2;
        const int o0 = (wg - 160) * 32;
        v4f acc[2];
        tile_gemm64x32(a5, Uh1b + (size_t)(2048 + o0) * HDIM, w, l, acc);
        const float* xp = xp1 + (t5 & 1) * (BAT * 3 * HDIM);
#pragma unroll
        for (int fc = 0; fc < 2; ++fc)
#pragma unroll
          for (int r = 0; r < 4; ++r) {
            int b = rbase + r;
            int o = o0 + fc * 16 + lr;
            float ht = tanh_f(xp[b * 3072 + 2048 + o] + acc[fc][r] + b1[2 * HDIM + o]);
            float z = z1[b * HDIM + o];
            float hn = (1.f - z) * h1f[b * HDIM + o] + z * ht;
            h1f[b * HDIM + o] = hn;
            u16 hb = f2bf(hn);
            h1b[b * HDIM + o] = hb;
            hs1[((size_t)t5 * BAT + b) * HDIM + o] = hb;
            if (t5 == SLEN - 1) outh[(size_t)BAT * HDIM + b * HDIM + o] = hn;
          }
      }
    }
    gbar(bar);
    // ---------------- Phase 2 ----------------
    if (wg < 32) {
      if (T < SLEN) {
        const int o0 = wg * 32;
        v4f acc[2];
        tile_gemm64x32(a2, Uh0b + (size_t)(2048 + o0) * HDIM, w, l, acc);
#pragma unroll
        for (int fc = 0; fc < 2; ++fc)
#pragma unroll
          for (int r = 0; r < 4; ++r) {
            int b = rbase + r;
            int o = o0 + fc * 16 + lr;
            float ht = tanh_f(bf2f(xa0[((T * 3 + 2) * BAT + b) * HDIM + o]) + acc[fc][r] + b0[2 * HDIM + o]);
            float z = z0[b * HDIM + o];
            float hn = (1.f - z) * h0f[b * HDIM + o] + z * ht;
            h0f[b * HDIM + o] = hn;
            h0b[b * HDIM + o] = f2bf(hn);
            if (T == SLEN - 1) outh[b * HDIM + o] = hn;
          }
      }
    } else if (wg < 96) {
      if (T >= 1 && T <= SLEN) {
        const int t4 = T - 1;
        const int c0 = (wg - 32) * 32;
        const int g = c0 >> 10;
        const int o0 = c0 & 1023;
        v4f acc[2];
        tile_gemm64x32(h1b, Uh1b + (size_t)c0 * HDIM, w, l, acc);
        const float* xp = xp1 + (t4 & 1) * (BAT * 3 * HDIM);
#pragma unroll
        for (int fc = 0; fc < 2; ++fc)
#pragma unroll
          for (int r = 0; r < 4; ++r) {
            int b = rbase + r;
            int o = o0 + fc * 16 + lr;
            float x = acc[fc][r] + xp[b * 3072 + g * HDIM + o] + b1[g * HDIM + o];
            float s = sigm(x);
            if (g == 0) a5[b * HDIM + o] = f2bf(s * h1f[b * HDIM + o]);
            else        z1[b * HDIM + o] = s;
          }
      }
    }
    gbar(bar);
  }
}

// ---------------- m97-style 128x128 bf16 GEMM ------------------------------------
// MODE 0: xa0 = gather(emb)[8192,512] x Wx0[3072,512]^T -> bf16 out in (S,3,B,H) layout
// MODE 1: logits = hs1[8192,1024] x Wd[VPAD,1024]^T + bd -> f32 (8192,10000)
template <int MODE>
__global__ void __launch_bounds__(256) k_gemm(
    const u16* __restrict__ A, const u16* __restrict__ Bw,
    const int* __restrict__ gidx, const float* __restrict__ bias,
    void* __restrict__ Out) {
  constexpr int K = MODE ? 1024 : 512;
  constexpr int NB_N = MODE ? (VPAD / 128) : (3072 / 128);

  __shared__ u16 sA[128 * 64];
  __shared__ u16 sB[128 * 64];

  const int nwg = gridDim.x;
  const int cpx = nwg >> 3;               // nwg % 8 == 0 for both grids
  const int bid = blockIdx.x;
  const int swz = (bid & 7) * cpx + (bid >> 3);
  const int bm = swz / NB_N, bn = swz % NB_N;
  const int m0 = bm * 128, n0 = bn * 128;

  const int t = threadIdx.x;
  const int w = t >> 6, l = t & 63;
  const int lr = l & 15, lk = (l >> 4) * 8;
  const int wm = (w >> 1) * 64, wn = (w & 1) * 64;
  const int kc = (t & 7) * 8;

  int arowg[4];
#pragma unroll
  for (int i = 0; i < 4; ++i) {
    int row = m0 + i * 32 + (t >> 3);
    arowg[i] = (MODE == 0) ? gidx[row] : row;
  }
  int brow[4];
#pragma unroll
  for (int i = 0; i < 4; ++i) brow[i] = n0 + i * 32 + (t >> 3);

  v4f acc[4][4];
#pragma unroll
  for (int mi = 0; mi < 4; ++mi)
#pragma unroll
    for (int ni = 0; ni < 4; ++ni) acc[mi][ni] = v4f{0.f, 0.f, 0.f, 0.f};

  for (int k0 = 0; k0 < K; k0 += 64) {
    __syncthreads();
#pragma unroll
    for (int i = 0; i < 4; ++i) {
      const u16* src = A + (size_t)arowg[i] * K + k0 + kc;
      __builtin_amdgcn_global_load_lds((const __attribute__((address_space(1))) void*)src,
                                       (__attribute__((address_space(3))) void*)(sA + i * 2048 + w * 512),
                                       16, 0, 0);
    }
#pragma unroll
    for (int i = 0; i < 4; ++i) {
      const u16* src = Bw + (size_t)brow[i] * K + k0 + kc;
      __builtin_amdgcn_global_load_lds((const __attribute__((address_space(1))) void*)src,
                                       (__attribute__((address_space(3))) void*)(sB + i * 2048 + w * 512),
                                       16, 0, 0);
    }
    asm volatile("s_waitcnt vmcnt(0)" ::: "memory");
    __syncthreads();
#pragma unroll
    for (int ks = 0; ks < 2; ++ks) {
      v8s af[4], bfr[4];
#pragma unroll
      for (int mi = 0; mi < 4; ++mi) af[mi] = *(const v8s*)&sA[(wm + mi * 16 + lr) * 64 + ks * 32 + lk];
#pragma unroll
      for (int ni = 0; ni < 4; ++ni) bfr[ni] = *(const v8s*)&sB[(wn + ni * 16 + lr) * 64 + ks * 32 + lk];
#pragma unroll
      for (int mi = 0; mi < 4; ++mi)
#pragma unroll
        for (int ni = 0; ni < 4; ++ni)
          acc[mi][ni] = __builtin_amdgcn_mfma_f32_16x16x32_bf16(af[mi], bfr[ni], acc[mi][ni], 0, 0, 0);
    }
  }

#pragma unroll
  for (int mi = 0; mi < 4; ++mi)
#pragma unroll
    for (int ni = 0; ni < 4; ++ni)
#pragma unroll
      for (int r = 0; r < 4; ++r) {
        int grow = m0 + wm + mi * 16 + ((l >> 4) << 2) + r;
        int gcol = n0 + wn + ni * 16 + lr;
        float v = acc[mi][ni][r];
        if (MODE == 0) {
          int s = grow >> 6, b = grow & 63;
          int g = gcol >> 10, o = gcol & 1023;
          ((u16*)Out)[(((size_t)s * 3 + g) * BAT + b) * HDIM + o] = f2bf(v);
        } else {
          if (gcol < VOC) ((float*)Out)[(size_t)grow * VOC + gcol] = v + bias[gcol];
        }
      }
}

// ---------------- small helper kernels --------------------------------------------
__global__ void k_cvt(const float* __restrict__ src, u16* __restrict__ dst, int n, int nsrc) {
  int i = (blockIdx.x * 256 + threadIdx.x) * 4;
  if (i >= n) return;
#pragma unroll
  for (int j = 0; j < 4; ++j) {
    int idx = i + j;
    if (idx < n) dst[idx] = (idx < nsrc) ? f2bf(src[idx]) : (u16)0;
  }
}

__global__ void k_init(const float* __restrict__ hidden,
                       float* h0f, u16* h0b, float* h1f, u16* h1b, int* bar) {
  int i = blockIdx.x * 256 + threadIdx.x;
  if (i < BAT * HDIM) {
    float v0 = hidden[i];
    float v1 = hidden[BAT * HDIM + i];
    h0f[i] = v0; h0b[i] = f2bf(v0);
    h1f[i] = v1; h1b[i] = f2bf(v1);
  }
  if (i < 512) bar[i] = 0;
}

// ---------------- launcher ---------------------------------------------------------
extern "C" void kernel_launch(void* const* d_in, const int* in_sizes, int n_in,
                              void* d_out, int out_size, void* d_ws, size_t ws_size,
                              hipStream_t stream) {
  const int*   inp = (const int*)d_in[0];
  const float* hid = (const float*)d_in[1];
  const float* emb = (const float*)d_in[2];
  const float* Wx0 = (const float*)d_in[3];
  const float* Uh0 = (const float*)d_in[4];
  const float* b0  = (const float*)d_in[5];
  const float* Wx1 = (const float*)d_in[6];
  const float* Uh1 = (const float*)d_in[7];
  const float* b1  = (const float*)d_in[8];
  const float* Wd  = (const float*)d_in[9];
  const float* bd  = (const float*)d_in[10];

  char* ws = (char*)d_ws;
  size_t off = 0;
  auto alloc = [&](size_t bytes) {
    void* p = ws + off;
    off = (off + bytes + 255) & ~(size_t)255;
    return p;
  };
  u16* emb_b = (u16*)alloc(sizeof(u16) * (size_t)VOC * EDIM);
  u16* Wx0_b = (u16*)alloc(sizeof(u16) * 3 * HDIM * EDIM);
  u16* Uh0_b = (u16*)alloc(sizeof(u16) * 3 * HDIM * HDIM);
  u16* Wx1_b = (u16*)alloc(sizeof(u16) * 3 * HDIM * HDIM);
  u16* Uh1_b = (u16*)alloc(sizeof(u16) * 3 * HDIM * HDIM);
  u16* Wd_b  = (u16*)alloc(sizeof(u16) * (size_t)VPAD * HDIM);
  u16* xa0_b = (u16*)alloc(sizeof(u16) * (size_t)SLEN * 3 * BAT * HDIM);
  u16* hs1_b = (u16*)alloc(sizeof(u16) * (size_t)SLEN * BAT * HDIM);
  float* xp1 = (float*)alloc(sizeof(float) * 2 * BAT * 3 * HDIM);
  float* h0f = (float*)alloc(sizeof(float) * BAT * HDIM);
  float* h1f = (float*)alloc(sizeof(float) * BAT * HDIM);
  u16* h0b   = (u16*)alloc(sizeof(u16) * BAT * HDIM);
  u16* h1b   = (u16*)alloc(sizeof(u16) * BAT * HDIM);
  u16* a2    = (u16*)alloc(sizeof(u16) * BAT * HDIM);
  u16* a5    = (u16*)alloc(sizeof(u16) * BAT * HDIM);
  float* z0  = (float*)alloc(sizeof(float) * BAT * HDIM);
  float* z1  = (float*)alloc(sizeof(float) * BAT * HDIM);
  int* bar   = (int*)alloc(sizeof(int) * 512);

  float* logits = (float*)d_out;
  float* outh = logits + (size_t)SLEN * BAT * VOC;

  auto cvt = [&](const float* s, u16* d, int n, int nsrc) {
    k_cvt<<<dim3((n / 4 + 255) / 256), dim3(256), 0, stream>>>(s, d, n, nsrc);
  };
  cvt(emb, emb_b, VOC * EDIM, VOC * EDIM);
  cvt(Wx0, Wx0_b, 3 * HDIM * EDIM, 3 * HDIM * EDIM);
  cvt(Uh0, Uh0_b, 3 * HDIM * HDIM, 3 * HDIM * HDIM);
  cvt(Wx1, Wx1_b, 3 * HDIM * HDIM, 3 * HDIM * HDIM);
  cvt(Uh1, Uh1_b, 3 * HDIM * HDIM, 3 * HDIM * HDIM);
  cvt(Wd, Wd_b, VPAD * HDIM, VOC * HDIM);
  k_init<<<dim3(256), dim3(256), 0, stream>>>(hid, h0f, h0b, h1f, h1b, bar);

  k_gemm<0><<<dim3(64 * 24), dim3(256), 0, stream>>>(emb_b, Wx0_b, inp, (const float*)nullptr, (void*)xa0_b);

  k_recur<<<dim3(NWG_REC), dim3(256), 0, stream>>>(
      Uh0_b, Wx1_b, Uh1_b, b0, b1, xa0_b,
      h0f, h0b, h1f, h1b, a2, z0, a5, z1, xp1, hs1_b, outh, bar);

  k_gemm<1><<<dim3(64 * 79), dim3(256), 0, stream>>>(hs1_b, Wd_b, (const int*)nullptr, bd, d_out);
}

// Round 2
// 4860.706 us; speedup vs baseline: 1.2651x; 1.2651x over previous
//
#include <hip/hip_runtime.h>
#include <hip/hip_bf16.h>

#define SLEN 128
#define BAT 64
#define EDIM 512
#define HDIM 1024
#define VOC 10000
#define VPAD 10112     // 79 * 128
#define NWG_REC 192
#define TPB_REC 512

typedef short v8s __attribute__((ext_vector_type(8)));
typedef float v4f __attribute__((ext_vector_type(4)));
typedef unsigned short u16;

__device__ __forceinline__ u16 f2bf(float f) {
  unsigned u = __float_as_uint(f);
  u += 0x7fffu + ((u >> 16) & 1u);   // RNE
  return (u16)(u >> 16);
}
__device__ __forceinline__ float bf2f(u16 b) {
  return __uint_as_float(((unsigned)b) << 16);
}
__device__ __forceinline__ float sigm(float x) { return 1.f / (1.f + __expf(-x)); }
__device__ __forceinline__ float tanh_f(float x) { return 1.f - 2.f / (1.f + __expf(2.f * x)); }

// ---------------- hierarchical grid barrier (192 WGs, 8 sub-counters) -------------
__device__ __forceinline__ void gbar(int* bar) {
  __syncthreads();
  if (threadIdx.x == 0) {
    int grp = blockIdx.x & 7;
    int* sub  = bar + grp * 32;      // 128B apart
    int* root = bar + 256;
    int* gen  = bar + 288;
    const int per = NWG_REC / 8;     // 24
    int g = __hip_atomic_load(gen, __ATOMIC_RELAXED, __HIP_MEMORY_SCOPE_AGENT);
    int a = __hip_atomic_fetch_add(sub, 1, __ATOMIC_ACQ_REL, __HIP_MEMORY_SCOPE_AGENT);
    if (a == per - 1) {
      __hip_atomic_store(sub, 0, __ATOMIC_RELAXED, __HIP_MEMORY_SCOPE_AGENT);
      int r = __hip_atomic_fetch_add(root, 1, __ATOMIC_ACQ_REL, __HIP_MEMORY_SCOPE_AGENT);
      if (r == 7) {
        __hip_atomic_store(root, 0, __ATOMIC_RELAXED, __HIP_MEMORY_SCOPE_AGENT);
        __hip_atomic_fetch_add(gen, 1, __ATOMIC_RELEASE, __HIP_MEMORY_SCOPE_AGENT);
      }
    }
    while (__hip_atomic_load(gen, __ATOMIC_RELAXED, __HIP_MEMORY_SCOPE_AGENT) == g)
      __builtin_amdgcn_s_sleep(2);
    __builtin_amdgcn_fence(__ATOMIC_ACQUIRE, "agent");
  }
  __syncthreads();
}

// One 16x16x1024 GEMM tile: A (16 rows from batch-major global), B from swizzled LDS.
// Lane l: lr=l&15 is both A-row and B-col index; lk=(l>>4)*8 is k element offset.
__device__ __forceinline__ v4f gemm16(const u16* __restrict__ A,
                                      const char* __restrict__ Blds,
                                      int rg, int cg, int lr, int lk) {
  const u16* ap = A + (rg * 16 + lr) * HDIM + lk;
  const int c = cg * 16 + lr;              // local weight column 0..31
  const int swz = (c & 7) << 4;
  const char* bbase = Blds + c * 2048;
  const int lk2 = lk * 2;
  v4f acc{0.f, 0.f, 0.f, 0.f};
#pragma unroll 8
  for (int ks = 0; ks < 32; ++ks) {
    v8s a = *(const v8s*)(ap + ks * 32);
    v8s b = *(const v8s*)(bbase + ((ks * 64 + lk2) ^ swz));
    acc = __builtin_amdgcn_mfma_f32_16x16x32_bf16(a, b, acc, 0, 0, 0);
  }
  return acc;
}

// ---------------- persistent 2-layer GRU recurrence -------------------------------
// Weights persist in LDS (96KB/WG, swizzled), loaded once before the T-loop.
// Per tick T (2 barriers):
//  P1 (8 waves: rg=w>>1, cg=w&1, 32 cols/WG):
//    rz0(T)    wg 0..63   A=h0b B=Uh0[rz]  -> a2,z0
//    xp1(T-1)  wg 64..159 A=h0b B=Wx1      -> xp1 buffer
//    ht1(T-2)  wg 160..191 A=a5 B=Uh1[h]   -> h1 update + hs1
//  P2 (waves 0..3, 16 cols/WG):
//    ht0(T)    wg 0..63   A=a2 B=Uh0[h]    -> h0 update
//    rz1(T-1)  wg 64..191 A=h1b B=Uh1[rz]  -> a5,z1
__global__ void __launch_bounds__(512, 2) k_recur(
    const u16* __restrict__ Uh0b, const u16* __restrict__ Wx1b, const u16* __restrict__ Uh1b,
    const float* __restrict__ b0, const float* __restrict__ b1,
    const u16* __restrict__ xa0,
    float* __restrict__ h0f, u16* __restrict__ h0b,
    float* __restrict__ h1f, u16* __restrict__ h1b,
    u16* __restrict__ a2, float* __restrict__ z0,
    u16* __restrict__ a5, float* __restrict__ z1,
    float* __restrict__ xp1,
    u16* __restrict__ hs1,
    float* __restrict__ outh,
    int* __restrict__ bar) {
  extern __shared__ char smem[];     // [0,64K): P1 weights (32 cols); [64K,96K): P2 (16 cols)
  const int wg = blockIdx.x;
  const int t = threadIdx.x;
  const int w = t >> 6;
  const int l = t & 63;
  const int lr = l & 15;
  const int lk = (l >> 4) * 8;
  const int rg = w >> 1, cg = w & 1;
  const int rbase1 = rg * 16 + ((l >> 4) << 2);
  const int rbase2 = w * 16 + ((l >> 4) << 2);

  // ---- one-time weight staging into swizzled LDS ----
  {
    const u16* w1src; int w1row0;
    if (wg < 64)       { w1src = Uh0b; w1row0 = wg * 32; }
    else if (wg < 160) { w1src = Wx1b; w1row0 = (wg - 64) * 32; }
    else               { w1src = Uh1b; w1row0 = 2048 + (wg - 160) * 32; }
    const u16* w2src; int w2row0;
    if (wg < 64) { w2src = Uh0b; w2row0 = 2048 + wg * 16; }
    else         { w2src = Uh1b; w2row0 = (wg - 64) * 16; }
    for (int i = t; i < 4096; i += TPB_REC) {          // 32 cols * 128 x 16B
      int c = i >> 7, j = i & 127;
      v8s v = *(const v8s*)(w1src + (size_t)(w1row0 + c) * HDIM + j * 8);
      int off = c * 2048 + ((j * 16) ^ ((c & 7) << 4));
      *(v8s*)(smem + off) = v;
    }
    for (int i = t; i < 2048; i += TPB_REC) {          // 16 cols * 128 x 16B
      int c = i >> 7, j = i & 127;
      v8s v = *(const v8s*)(w2src + (size_t)(w2row0 + c) * HDIM + j * 8);
      int off = 65536 + c * 2048 + ((j * 16) ^ ((c & 7) << 4));
      *(v8s*)(smem + off) = v;
    }
    __syncthreads();
  }

  for (int T = 0; T <= SLEN + 1; ++T) {
    // ---------------- Phase 1 ----------------
    if (wg < 64) {
      if (T < SLEN) {
        v4f acc = gemm16(h0b, smem, rg, cg, lr, lk);
        const int cglob = wg * 32 + cg * 16 + lr;      // 0..2047
        const int g = cglob >> 10;                     // uniform per WG
        const int o = cglob & 1023;
        const float bias = b0[g * HDIM + o];
#pragma unroll
        for (int r = 0; r < 4; ++r) {
          int b = rbase1 + r;
          float x = acc[r] + bf2f(xa0[((T * 3 + g) * BAT + b) * HDIM + o]) + bias;
          float s = sigm(x);
          if (g == 0) a2[b * HDIM + o] = f2bf(s * h0f[b * HDIM + o]);
          else        z0[b * HDIM + o] = s;
        }
      }
    } else if (wg < 160) {
      if (T >= 1 && T <= SLEN) {
        v4f acc = gemm16(h0b, smem, rg, cg, lr, lk);
        const int n = (wg - 64) * 32 + cg * 16 + lr;   // 0..3071
        float* xp = xp1 + ((T - 1) & 1) * (BAT * 3 * HDIM);
#pragma unroll
        for (int r = 0; r < 4; ++r) xp[(rbase1 + r) * 3072 + n] = acc[r];
      }
    } else {
      if (T >= 2) {
        const int t5 = T - 2;
        v4f acc = gemm16(a5, smem, rg, cg, lr, lk);
        const int o = (wg - 160) * 32 + cg * 16 + lr;  // 0..1023
        const float* xp = xp1 + (t5 & 1) * (BAT * 3 * HDIM);
        const float bias = b1[2 * HDIM + o];
#pragma unroll
        for (int r = 0; r < 4; ++r) {
          int b = rbase1 + r;
          float ht = tanh_f(xp[b * 3072 + 2048 + o] + acc[r] + bias);
          float z = z1[b * HDIM + o];
          float hn = (1.f - z) * h1f[b * HDIM + o] + z * ht;
          h1f[b * HDIM + o] = hn;
          u16 hb = f2bf(hn);
          h1b[b * HDIM + o] = hb;
          hs1[((size_t)t5 * BAT + b) * HDIM + o] = hb;
          if (t5 == SLEN - 1) outh[(size_t)BAT * HDIM + b * HDIM + o] = hn;
        }
      }
    }
    gbar(bar);
    // ---------------- Phase 2 (waves 0..3 only) ----------------
    if (w < 4) {
      if (wg < 64) {
        if (T < SLEN) {
          v4f acc = gemm16(a2, smem + 65536, w, 0, lr, lk);
          const int o = wg * 16 + lr;                  // 0..1023
          const float bias = b0[2 * HDIM + o];
#pragma unroll
          for (int r = 0; r < 4; ++r) {
            int b = rbase2 + r;
            float ht = tanh_f(bf2f(xa0[((T * 3 + 2) * BAT + b) * HDIM + o]) + acc[r] + bias);
            float z = z0[b * HDIM + o];
            float hn = (1.f - z) * h0f[b * HDIM + o] + z * ht;
            h0f[b * HDIM + o] = hn;
            h0b[b * HDIM + o] = f2bf(hn);
            if (T == SLEN - 1) outh[b * HDIM + o] = hn;
          }
        }
      } else {
        if (T >= 1 && T <= SLEN) {
          const int t4 = T - 1;
          v4f acc = gemm16(h1b, smem + 65536, w, 0, lr, lk);
          const int cglob = (wg - 64) * 16 + lr;       // 0..2047
          const int g = cglob >> 10;                   // uniform per WG
          const int o = cglob & 1023;
          const float* xp = xp1 + (t4 & 1) * (BAT * 3 * HDIM);
          const float bias = b1[g * HDIM + o];
#pragma unroll
          for (int r = 0; r < 4; ++r) {
            int b = rbase2 + r;
            float x = acc[r] + xp[b * 3072 + g * HDIM + o] + bias;
            float s = sigm(x);
            if (g == 0) a5[b * HDIM + o] = f2bf(s * h1f[b * HDIM + o]);
            else        z1[b * HDIM + o] = s;
          }
        }
      }
    }
    gbar(bar);
  }
}

// ---------------- m97-style 128x128 bf16 GEMM ------------------------------------
// MODE 0: xa0 = gather(emb)[8192,512] x Wx0[3072,512]^T -> bf16 out in (S,3,B,H) layout
// MODE 1: logits = hs1[8192,1024] x Wd[VPAD,1024]^T + bd -> f32 (8192,10000)
template <int MODE>
__global__ void __launch_bounds__(256) k_gemm(
    const u16* __restrict__ A, const u16* __restrict__ Bw,
    const int* __restrict__ gidx, const float* __restrict__ bias,
    void* __restrict__ Out) {
  constexpr int K = MODE ? 1024 : 512;
  constexpr int NB_N = MODE ? (VPAD / 128) : (3072 / 128);

  __shared__ u16 sA[128 * 64];
  __shared__ u16 sB[128 * 64];

  const int nwg = gridDim.x;
  const int cpx = nwg >> 3;               // nwg % 8 == 0 for both grids
  const int bid = blockIdx.x;
  const int swz = (bid & 7) * cpx + (bid >> 3);
  const int bm = swz / NB_N, bn = swz % NB_N;
  const int m0 = bm * 128, n0 = bn * 128;

  const int t = threadIdx.x;
  const int w = t >> 6, l = t & 63;
  const int lr = l & 15, lk = (l >> 4) * 8;
  const int wm = (w >> 1) * 64, wn = (w & 1) * 64;
  const int kc = (t & 7) * 8;

  int arowg[4];
#pragma unroll
  for (int i = 0; i < 4; ++i) {
    int row = m0 + i * 32 + (t >> 3);
    arowg[i] = (MODE == 0) ? gidx[row] : row;
  }
  int brow[4];
#pragma unroll
  for (int i = 0; i < 4; ++i) brow[i] = n0 + i * 32 + (t >> 3);

  v4f acc[4][4];
#pragma unroll
  for (int mi = 0; mi < 4; ++mi)
#pragma unroll
    for (int ni = 0; ni < 4; ++ni) acc[mi][ni] = v4f{0.f, 0.f, 0.f, 0.f};

  for (int k0 = 0; k0 < K; k0 += 64) {
    __syncthreads();
#pragma unroll
    for (int i = 0; i < 4; ++i) {
      const u16* src = A + (size_t)arowg[i] * K + k0 + kc;
      __builtin_amdgcn_global_load_lds((const __attribute__((address_space(1))) void*)src,
                                       (__attribute__((address_space(3))) void*)(sA + i * 2048 + w * 512),
                                       16, 0, 0);
    }
#pragma unroll
    for (int i = 0; i < 4; ++i) {
      const u16* src = Bw + (size_t)brow[i] * K + k0 + kc;
      __builtin_amdgcn_global_load_lds((const __attribute__((address_space(1))) void*)src,
                                       (__attribute__((address_space(3))) void*)(sB + i * 2048 + w * 512),
                                       16, 0, 0);
    }
    asm volatile("s_waitcnt vmcnt(0)" ::: "memory");
    __syncthreads();
#pragma unroll
    for (int ks = 0; ks < 2; ++ks) {
      v8s af[4], bfr[4];
#pragma unroll
      for (int mi = 0; mi < 4; ++mi) af[mi] = *(const v8s*)&sA[(wm + mi * 16 + lr) * 64 + ks * 32 + lk];
#pragma unroll
      for (int ni = 0; ni < 4; ++ni) bfr[ni] = *(const v8s*)&sB[(wn + ni * 16 + lr) * 64 + ks * 32 + lk];
#pragma unroll
      for (int mi = 0; mi < 4; ++mi)
#pragma unroll
        for (int ni = 0; ni < 4; ++ni)
          acc[mi][ni] = __builtin_amdgcn_mfma_f32_16x16x32_bf16(af[mi], bfr[ni], acc[mi][ni], 0, 0, 0);
    }
  }

#pragma unroll
  for (int mi = 0; mi < 4; ++mi)
#pragma unroll
    for (int ni = 0; ni < 4; ++ni)
#pragma unroll
      for (int r = 0; r < 4; ++r) {
        int grow = m0 + wm + mi * 16 + ((l >> 4) << 2) + r;
        int gcol = n0 + wn + ni * 16 + lr;
        float v = acc[mi][ni][r];
        if (MODE == 0) {
          int s = grow >> 6, b = grow & 63;
          int g = gcol >> 10, o = gcol & 1023;
          ((u16*)Out)[(((size_t)s * 3 + g) * BAT + b) * HDIM + o] = f2bf(v);
        } else {
          if (gcol < VOC) ((float*)Out)[(size_t)grow * VOC + gcol] = v + bias[gcol];
        }
      }
}

// ---------------- small helper kernels --------------------------------------------
__global__ void k_cvt(const float* __restrict__ src, u16* __restrict__ dst, int n, int nsrc) {
  int i = (blockIdx.x * 256 + threadIdx.x) * 4;
  if (i >= n) return;
#pragma unroll
  for (int j = 0; j < 4; ++j) {
    int idx = i + j;
    if (idx < n) dst[idx] = (idx < nsrc) ? f2bf(src[idx]) : (u16)0;
  }
}

__global__ void k_init(const float* __restrict__ hidden,
                       float* h0f, u16* h0b, float* h1f, u16* h1b, int* bar) {
  int i = blockIdx.x * 256 + threadIdx.x;
  if (i < BAT * HDIM) {
    float v0 = hidden[i];
    float v1 = hidden[BAT * HDIM + i];
    h0f[i] = v0; h0b[i] = f2bf(v0);
    h1f[i] = v1; h1b[i] = f2bf(v1);
  }
  if (i < 512) bar[i] = 0;
}

// ---------------- launcher ---------------------------------------------------------
extern "C" void kernel_launch(void* const* d_in, const int* in_sizes, int n_in,
                              void* d_out, int out_size, void* d_ws, size_t ws_size,
                              hipStream_t stream) {
  const int*   inp = (const int*)d_in[0];
  const float* hid = (const float*)d_in[1];
  const float* emb = (const float*)d_in[2];
  const float* Wx0 = (const float*)d_in[3];
  const float* Uh0 = (const float*)d_in[4];
  const float* b0  = (const float*)d_in[5];
  const float* Wx1 = (const float*)d_in[6];
  const float* Uh1 = (const float*)d_in[7];
  const float* b1  = (const float*)d_in[8];
  const float* Wd  = (const float*)d_in[9];
  const float* bd  = (const float*)d_in[10];

  char* ws = (char*)d_ws;
  size_t off = 0;
  auto alloc = [&](size_t bytes) {
    void* p = ws + off;
    off = (off + bytes + 255) & ~(size_t)255;
    return p;
  };
  u16* emb_b = (u16*)alloc(sizeof(u16) * (size_t)VOC * EDIM);
  u16* Wx0_b = (u16*)alloc(sizeof(u16) * 3 * HDIM * EDIM);
  u16* Uh0_b = (u16*)alloc(sizeof(u16) * 3 * HDIM * HDIM);
  u16* Wx1_b = (u16*)alloc(sizeof(u16) * 3 * HDIM * HDIM);
  u16* Uh1_b = (u16*)alloc(sizeof(u16) * 3 * HDIM * HDIM);
  u16* Wd_b  = (u16*)alloc(sizeof(u16) * (size_t)VPAD * HDIM);
  u16* xa0_b = (u16*)alloc(sizeof(u16) * (size_t)SLEN * 3 * BAT * HDIM);
  u16* hs1_b = (u16*)alloc(sizeof(u16) * (size_t)SLEN * BAT * HDIM);
  float* xp1 = (float*)alloc(sizeof(float) * 2 * BAT * 3 * HDIM);
  float* h0f = (float*)alloc(sizeof(float) * BAT * HDIM);
  float* h1f = (float*)alloc(sizeof(float) * BAT * HDIM);
  u16* h0b   = (u16*)alloc(sizeof(u16) * BAT * HDIM);
  u16* h1b   = (u16*)alloc(sizeof(u16) * BAT * HDIM);
  u16* a2    = (u16*)alloc(sizeof(u16) * BAT * HDIM);
  u16* a5    = (u16*)alloc(sizeof(u16) * BAT * HDIM);
  float* z0  = (float*)alloc(sizeof(float) * BAT * HDIM);
  float* z1  = (float*)alloc(sizeof(float) * BAT * HDIM);
  int* bar   = (int*)alloc(sizeof(int) * 512);

  float* logits = (float*)d_out;
  float* outh = logits + (size_t)SLEN * BAT * VOC;

  auto cvt = [&](const float* s, u16* d, int n, int nsrc) {
    k_cvt<<<dim3((n / 4 + 255) / 256), dim3(256), 0, stream>>>(s, d, n, nsrc);
  };
  cvt(emb, emb_b, VOC * EDIM, VOC * EDIM);
  cvt(Wx0, Wx0_b, 3 * HDIM * EDIM, 3 * HDIM * EDIM);
  cvt(Uh0, Uh0_b, 3 * HDIM * HDIM, 3 * HDIM * HDIM);
  cvt(Wx1, Wx1_b, 3 * HDIM * HDIM, 3 * HDIM * HDIM);
  cvt(Uh1, Uh1_b, 3 * HDIM * HDIM, 3 * HDIM * HDIM);
  cvt(Wd, Wd_b, VPAD * HDIM, VOC * HDIM);
  k_init<<<dim3(256), dim3(256), 0, stream>>>(hid, h0f, h0b, h1f, h1b, bar);

  k_gemm<0><<<dim3(64 * 24), dim3(256), 0, stream>>>(emb_b, Wx0_b, inp, (const float*)nullptr, (void*)xa0_b);

  (void)hipFuncSetAttribute(reinterpret_cast<const void*>(k_recur),
                            hipFuncAttributeMaxDynamicSharedMemorySize, 96 * 1024);
  k_recur<<<dim3(NWG_REC), dim3(TPB_REC), 96 * 1024, stream>>>(
      Uh0_b, Wx1_b, Uh1_b, b0, b1, xa0_b,
      h0f, h0b, h1f, h1b, a2, z0, a5, z1, xp1, hs1_b, outh, bar);

  k_gemm<1><<<dim3(64 * 79), dim3(256), 0, stream>>>(hs1_b, Wd_b, (const int*)nullptr, bd, d_out);
}